// Round 6
// baseline (253.353 us; speedup 1.0000x reference)
//
#include <hip/hip_runtime.h>
#include <hip/hip_bf16.h>

#define TT 16384
#define DM 256
#define NE 8
#define HF 512
#define MAXT 520  // >= sum_e ceil(cnt_e/64), cnt sums to 32768

typedef __bf16 bf16x8 __attribute__((ext_vector_type(8)));
typedef float f32x4 __attribute__((ext_vector_type(4)));

__device__ __forceinline__ unsigned f2bf(float f) {
  unsigned u = __float_as_uint(f);
  u += 0x7fffu + ((u >> 16) & 1u);  // RNE
  return u >> 16;
}

// Dense tile decode: tile-index tb -> (expert e, token base, H slot base s0, cnt).
// Returns e=-1 if tb beyond the last active tile.
__device__ __forceinline__ int decode_tile(const int* __restrict__ cnts, int tb,
                                           int* base, int* s0, int* cnt) {
  int tp = 0, e = -1;
#pragma unroll
  for (int i = 0; i < NE; i++) {
    int c = cnts[i];
    int nt = (c + 63) >> 6;
    if (e < 0 && tb < tp + nt) { e = i; *base = (tb - tp) << 6; *s0 = tp << 6; *cnt = c; }
    tp += nt;
  }
  return e;
}

// ---- gate: thread=(token,expert), fp64 scores, top-2, list build, out=b2 init ----
__global__ __launch_bounds__(256) void gate_kernel(
    const float* __restrict__ x, const float* __restrict__ Wg,
    const float* __restrict__ bg, const float* __restrict__ b2,
    int* __restrict__ cnts, int* __restrict__ list, float* __restrict__ out) {
  __shared__ int hist[NE], base_s[NE], rank[NE];
  int tid = threadIdx.x;
  if (tid < NE) { hist[tid] = 0; rank[tid] = 0; }
  __syncthreads();

  int tl = tid >> 3, e = tid & 7, lane = tid & 63;
  int t = blockIdx.x * 32 + tl;
  const float* xr = x + (size_t)t * DM;
  double a0 = 0, a1 = 0, a2 = 0, a3 = 0;
  for (int d = 0; d < DM; d += 4) {
    float4 v = *reinterpret_cast<const float4*>(xr + d);
    a0 += (double)v.x * (double)Wg[(d + 0) * NE + e];
    a1 += (double)v.y * (double)Wg[(d + 1) * NE + e];
    a2 += (double)v.z * (double)Wg[(d + 2) * NE + e];
    a3 += (double)v.w * (double)Wg[(d + 3) * NE + e];
  }
  double s = ((a0 + a1) + (a2 + a3)) + (double)bg[e];

  double sc[8];
#pragma unroll
  for (int k = 0; k < 8; k++) sc[k] = __shfl(s, (lane & 56) | k);
  int e1 = 0;
#pragma unroll
  for (int k = 1; k < 8; k++) if (sc[k] > sc[e1]) e1 = k;  // ties -> lower index
  int e2 = -1;
#pragma unroll
  for (int k = 0; k < 8; k++) {
    if (k == e1) continue;
    if (e2 < 0 || sc[k] > sc[e2]) e2 = k;
  }

  if (e == 0) { atomicAdd(&hist[e1], 1); atomicAdd(&hist[e2], 1); }
  __syncthreads();
  if (tid < NE) base_s[tid] = atomicAdd(&cnts[tid], hist[tid]);
  __syncthreads();
  if (e == 0) {
    int r1 = atomicAdd(&rank[e1], 1);
    list[e1 * TT + base_s[e1] + r1] = t;
    int r2 = atomicAdd(&rank[e2], 1);
    list[e2 * TT + base_s[e2] + r2] = t;
  }

  const float* p1 = b2 + e1 * DM + e * 32;
  const float* p2 = b2 + e2 * DM + e * 32;
  float* orow = out + (size_t)t * DM + e * 32;
#pragma unroll
  for (int j = 0; j < 32; j += 4) {
    float4 u = *reinterpret_cast<const float4*>(p1 + j);
    float4 v = *reinterpret_cast<const float4*>(p2 + j);
    float4 o;
    o.x = u.x + v.x; o.y = u.y + v.y; o.z = u.z + v.z; o.w = u.w + v.w;
    *reinterpret_cast<float4*>(orow + j) = o;
  }
}

// ---- fused transpose+cast: W1 [D][H]->w1t[H][D], W2 [H][D]->w2t[D][H], bf16 ------
__global__ __launch_bounds__(256) void transpose_kernel(
    const float* __restrict__ W1, const float* __restrict__ W2,
    unsigned short* __restrict__ w1t, unsigned short* __restrict__ w2t) {
  __shared__ float tile[32][33];
  int bx = blockIdx.x;
  int which = bx >> 10;
  int rem = bx & 1023;
  int e = rem >> 7, t = rem & 127;
  const float* src;
  unsigned short* dst;
  int R, C, cx, ry;
  if (which == 0) {
    R = DM; C = HF;
    src = W1 + (size_t)e * R * C; dst = w1t + (size_t)e * R * C;
    cx = t & 15; ry = t >> 4;
  } else {
    R = HF; C = DM;
    src = W2 + (size_t)e * R * C; dst = w2t + (size_t)e * R * C;
    cx = t & 7; ry = t >> 3;
  }
  int c0 = cx * 32, r0 = ry * 32;
  int tx = threadIdx.x & 31, ty = threadIdx.x >> 5;
#pragma unroll
  for (int i = 0; i < 4; i++)
    tile[ty + i * 8][tx] = src[(size_t)(r0 + ty + i * 8) * C + c0 + tx];
  __syncthreads();
#pragma unroll
  for (int i = 0; i < 4; i++)
    dst[(size_t)(c0 + ty + i * 8) * R + r0 + tx] =
        (unsigned short)f2bf(tile[tx][ty + i * 8]);
}

// ---- G1: H[slot][h] = gelu(X @ W1^T + b1) --------------------------------------
// Block = (token tile of 64) x (h-half of 256). 256 thr, wave w owns 64 h's.
// m=token (A = Xf LDS frags), n=h (B = w1t rows, global), k=D. One barrier.
__global__ __launch_bounds__(256, 4) void g1_kernel(
    const float* __restrict__ x, const unsigned short* __restrict__ w1t,
    const float* __restrict__ b1, const int* __restrict__ cnts,
    const int* __restrict__ list, unsigned short* __restrict__ H) {
  __shared__ __align__(16) unsigned short Xf[64 * DM];  // 32 KB, A-frag order
  int bx = blockIdx.x;
  int hh = bx & 1, tb = bx >> 1;
  int base, s0, cnt;
  int e = decode_tile(cnts, tb, &base, &s0, &cnt);
  if (e < 0) return;

  int tid = threadIdx.x, w = tid >> 6, lane = tid & 63;
  int quad = lane >> 4, l16 = lane & 15;

  {  // stage Xf: wave w stages m-tile mt=w (lane-linear writes)
    int tl = w * 16 + l16;
    int token = (base + tl < cnt) ? list[e * TT + base + tl] : -1;
    unsigned short* dst0 = Xf + ((w * 8) * 64 + lane) * 8;
    if (token >= 0) {
      const float* xr = x + (size_t)token * DM + quad * 8;
#pragma unroll
      for (int ks = 0; ks < 8; ks++) {
        float4 v0 = *reinterpret_cast<const float4*>(xr + ks * 32);
        float4 v1 = *reinterpret_cast<const float4*>(xr + ks * 32 + 4);
        uint4 pk;
        pk.x = f2bf(v0.x) | (f2bf(v0.y) << 16);
        pk.y = f2bf(v0.z) | (f2bf(v0.w) << 16);
        pk.z = f2bf(v1.x) | (f2bf(v1.y) << 16);
        pk.w = f2bf(v1.z) | (f2bf(v1.w) << 16);
        *reinterpret_cast<uint4*>(dst0 + ks * 512) = pk;
      }
    } else {
      uint4 z = {0, 0, 0, 0};
#pragma unroll
      for (int ks = 0; ks < 8; ks++)
        *reinterpret_cast<uint4*>(dst0 + ks * 512) = z;
    }
  }
  __syncthreads();  // the only barrier

  int h0 = hh * 256 + w * 64;  // this wave's h-slice
  const unsigned short* w1p =
      w1t + (size_t)e * HF * DM + (size_t)(h0 + l16) * DM + quad * 8;
  f32x4 pacc[4][4];
#pragma unroll
  for (int mt = 0; mt < 4; mt++)
#pragma unroll
    for (int nt = 0; nt < 4; nt++) pacc[mt][nt] = (f32x4){0.f, 0.f, 0.f, 0.f};

#pragma unroll
  for (int ks = 0; ks < 8; ks++) {
    bf16x8 bfr[4], afr[4];
#pragma unroll
    for (int nt = 0; nt < 4; nt++)
      bfr[nt] = *reinterpret_cast<const bf16x8*>(w1p + (size_t)(nt * 16) * DM + ks * 32);
#pragma unroll
    for (int mt = 0; mt < 4; mt++)
      afr[mt] = *reinterpret_cast<const bf16x8*>(Xf + ((mt * 8 + ks) * 64 + lane) * 8);
#pragma unroll
    for (int mt = 0; mt < 4; mt++)
#pragma unroll
      for (int nt = 0; nt < 4; nt++)
        pacc[mt][nt] = __builtin_amdgcn_mfma_f32_16x16x32_bf16(afr[mt], bfr[nt], pacc[mt][nt], 0, 0, 0);
  }

  float b1v[4];
#pragma unroll
  for (int nt = 0; nt < 4; nt++) b1v[nt] = b1[e * HF + h0 + nt * 16 + l16];

#pragma unroll
  for (int mt = 0; mt < 4; mt++) {
    size_t hrow = (size_t)(s0 + base + mt * 16 + quad * 4) * HF + h0 + l16;
#pragma unroll
    for (int r = 0; r < 4; r++) {
#pragma unroll
      for (int nt = 0; nt < 4; nt++) {
        float v = pacc[mt][nt][r] + b1v[nt];
        float g = 0.5f * v * (1.0f + erff(v * 0.70710678118654752f));
        H[hrow + (size_t)r * HF + nt * 16] = (unsigned short)f2bf(g);
      }
    }
  }
}

// ---- G2: out += H @ W2^T, k-split x2, coalesced atomics --------------------------
// Block = (token tile of 64) x (k-half of 256). m=token, n=d, no LDS/barriers.
__global__ __launch_bounds__(256, 4) void g2_kernel(
    const unsigned short* __restrict__ H, const unsigned short* __restrict__ w2t,
    const int* __restrict__ cnts, const int* __restrict__ list,
    float* __restrict__ out) {
  int bx = blockIdx.x;
  int kh = bx & 1, tb = bx >> 1;
  int base, s0, cnt;
  int e = decode_tile(cnts, tb, &base, &s0, &cnt);
  if (e < 0) return;

  int tid = threadIdx.x, w = tid >> 6, lane = tid & 63;
  int quad = lane >> 4, l16 = lane & 15;

  const unsigned short* Hp = H + (size_t)(s0 + base + l16) * HF + kh * 256 + quad * 8;
  const unsigned short* w2p =
      w2t + (size_t)e * DM * HF + (size_t)(w * 64 + l16) * HF + kh * 256 + quad * 8;

  f32x4 oacc[4][4];
#pragma unroll
  for (int mt = 0; mt < 4; mt++)
#pragma unroll
    for (int nt = 0; nt < 4; nt++) oacc[mt][nt] = (f32x4){0.f, 0.f, 0.f, 0.f};

#pragma unroll
  for (int ks = 0; ks < 8; ks++) {
    bf16x8 ha[4], bfr[4];
#pragma unroll
    for (int mt = 0; mt < 4; mt++)
      ha[mt] = *reinterpret_cast<const bf16x8*>(Hp + (size_t)(mt * 16) * HF + ks * 32);
#pragma unroll
    for (int nt = 0; nt < 4; nt++)
      bfr[nt] = *reinterpret_cast<const bf16x8*>(w2p + (size_t)(nt * 16) * HF + ks * 32);
#pragma unroll
    for (int mt = 0; mt < 4; mt++)
#pragma unroll
      for (int nt = 0; nt < 4; nt++)
        oacc[mt][nt] = __builtin_amdgcn_mfma_f32_16x16x32_bf16(ha[mt], bfr[nt], oacc[mt][nt], 0, 0, 0);
  }

#pragma unroll
  for (int mt = 0; mt < 4; mt++) {
#pragma unroll
    for (int r = 0; r < 4; r++) {
      int row = base + mt * 16 + quad * 4 + r;
      if (row >= cnt) continue;
      int token = list[e * TT + row];
      float* orow = out + (size_t)token * DM + w * 64;
#pragma unroll
      for (int nt = 0; nt < 4; nt++)
        atomicAdd(orow + nt * 16 + l16, oacc[mt][nt][r]);
    }
  }
}

extern "C" void kernel_launch(void* const* d_in, const int* in_sizes, int n_in,
                              void* d_out, int out_size, void* d_ws, size_t ws_size,
                              hipStream_t stream) {
  (void)in_sizes; (void)n_in; (void)out_size; (void)ws_size;
  const float* x  = (const float*)d_in[0];
  const float* Wg = (const float*)d_in[1];
  const float* bg = (const float*)d_in[2];
  const float* W1 = (const float*)d_in[3];
  const float* b1 = (const float*)d_in[4];
  const float* W2 = (const float*)d_in[5];
  const float* b2 = (const float*)d_in[6];
  float* out = (float*)d_out;

  char* ws = (char*)d_ws;
  int* cnts = (int*)ws;                                                  // 256 B
  int* list = (int*)(ws + 256);                                          // 512 KB
  unsigned short* w1t = (unsigned short*)(ws + 256 + 524288);            // 2 MB
  unsigned short* w2t = (unsigned short*)(ws + 256 + 524288 + 2097152);  // 2 MB
  size_t off_H = 256 + 524288 + 2097152 + 2097152;
  unsigned short* Hbuf = (unsigned short*)(ws + off_H);  // (32768+8*64)*512*2 ~ 34 MB

  hipMemsetAsync(cnts, 0, 256, stream);

  hipLaunchKernelGGL(gate_kernel, dim3(TT / 32), dim3(256), 0, stream,
                     x, Wg, bg, b2, cnts, list, out);
  hipLaunchKernelGGL(transpose_kernel, dim3(2 * NE * 128), dim3(256), 0, stream,
                     W1, W2, w1t, w2t);
  hipLaunchKernelGGL(g1_kernel, dim3(2 * MAXT), dim3(256), 0, stream,
                     x, w1t, b1, cnts, list, Hbuf);
  hipLaunchKernelGGL(g2_kernel, dim3(2 * MAXT), dim3(256), 0, stream,
                     Hbuf, w2t, cnts, list, out);
}

// Round 7
// 235.422 us; speedup vs baseline: 1.0762x; 1.0762x over previous
//
#include <hip/hip_runtime.h>
#include <hip/hip_bf16.h>

#define TT 16384
#define DM 256
#define NE 8
#define HF 512
#define MAXT 520    // >= sum_e ceil(cnt_e/64)
#define MAXT32 1040 // >= sum_e padded64(cnt_e)/32

typedef __bf16 bf16x8 __attribute__((ext_vector_type(8)));
typedef float f32x4 __attribute__((ext_vector_type(4)));

__device__ __forceinline__ unsigned f2bf(float f) {
  unsigned u = __float_as_uint(f);
  u += 0x7fffu + ((u >> 16) & 1u);  // RNE
  return u >> 16;
}

// tile of 64 tokens -> (expert, token base, 64-padded slot base, cnt)
__device__ __forceinline__ int decode_tile(const int* __restrict__ cnts, int tb,
                                           int* base, int* s0, int* cnt) {
  int tp = 0, e = -1;
#pragma unroll
  for (int i = 0; i < NE; i++) {
    int c = cnts[i];
    int nt = (c + 63) >> 6;
    if (e < 0 && tb < tp + nt) { e = i; *base = (tb - tp) << 6; *s0 = tp << 6; *cnt = c; }
    tp += nt;
  }
  return e;
}

// tile of 32 tokens over the 64-padded slot space -> (expert, base, slot base)
__device__ __forceinline__ int decode_tile32(const int* __restrict__ cnts, int tb,
                                             int* base, int* s0) {
  int tp = 0, sp = 0, e = -1;
#pragma unroll
  for (int i = 0; i < NE; i++) {
    int p = (cnts[i] + 63) & ~63;
    int nt = p >> 5;
    if (e < 0 && tb < tp + nt) { e = i; *base = (tb - tp) << 5; *s0 = sp; }
    tp += nt; sp += p;
  }
  return e;
}

// ---- gate: fp64 scores, top-2, list build + per-token packed (e,rank) slots ------
__global__ __launch_bounds__(256) void gate_kernel(
    const float* __restrict__ x, const float* __restrict__ Wg,
    const float* __restrict__ bg, int* __restrict__ cnts,
    int* __restrict__ list, uint2* __restrict__ slots) {
  __shared__ int hist[NE], base_s[NE], rank[NE];
  int tid = threadIdx.x;
  if (tid < NE) { hist[tid] = 0; rank[tid] = 0; }
  __syncthreads();

  int tl = tid >> 3, e = tid & 7, lane = tid & 63;
  int t = blockIdx.x * 32 + tl;
  const float* xr = x + (size_t)t * DM;
  double a0 = 0, a1 = 0, a2 = 0, a3 = 0;
  for (int d = 0; d < DM; d += 4) {
    float4 v = *reinterpret_cast<const float4*>(xr + d);
    a0 += (double)v.x * (double)Wg[(d + 0) * NE + e];
    a1 += (double)v.y * (double)Wg[(d + 1) * NE + e];
    a2 += (double)v.z * (double)Wg[(d + 2) * NE + e];
    a3 += (double)v.w * (double)Wg[(d + 3) * NE + e];
  }
  double s = ((a0 + a1) + (a2 + a3)) + (double)bg[e];

  double sc[8];
#pragma unroll
  for (int k = 0; k < 8; k++) sc[k] = __shfl(s, (lane & 56) | k);
  int e1 = 0;
#pragma unroll
  for (int k = 1; k < 8; k++) if (sc[k] > sc[e1]) e1 = k;  // ties -> lower index
  int e2 = -1;
#pragma unroll
  for (int k = 0; k < 8; k++) {
    if (k == e1) continue;
    if (e2 < 0 || sc[k] > sc[e2]) e2 = k;
  }

  if (e == 0) { atomicAdd(&hist[e1], 1); atomicAdd(&hist[e2], 1); }
  __syncthreads();
  if (tid < NE) base_s[tid] = atomicAdd(&cnts[tid], hist[tid]);
  __syncthreads();
  if (e == 0) {
    int r1 = base_s[e1] + atomicAdd(&rank[e1], 1);
    list[e1 * TT + r1] = t;
    int r2 = base_s[e2] + atomicAdd(&rank[e2], 1);
    list[e2 * TT + r2] = t;
    slots[t] = make_uint2(((unsigned)e1 << 14) | (unsigned)r1,
                          ((unsigned)e2 << 14) | (unsigned)r2);
  }
}

// ---- fused transpose+cast: W1 [D][H]->w1t[H][D], W2 [H][D]->w2t[D][H], bf16 ------
__global__ __launch_bounds__(256) void transpose_kernel(
    const float* __restrict__ W1, const float* __restrict__ W2,
    unsigned short* __restrict__ w1t, unsigned short* __restrict__ w2t) {
  __shared__ float tile[32][33];
  int bx = blockIdx.x;
  int which = bx >> 10;
  int rem = bx & 1023;
  int e = rem >> 7, t = rem & 127;
  const float* src;
  unsigned short* dst;
  int R, C, cx, ry;
  if (which == 0) {
    R = DM; C = HF;
    src = W1 + (size_t)e * R * C; dst = w1t + (size_t)e * R * C;
    cx = t & 15; ry = t >> 4;
  } else {
    R = HF; C = DM;
    src = W2 + (size_t)e * R * C; dst = w2t + (size_t)e * R * C;
    cx = t & 7; ry = t >> 3;
  }
  int c0 = cx * 32, r0 = ry * 32;
  int tx = threadIdx.x & 31, ty = threadIdx.x >> 5;
#pragma unroll
  for (int i = 0; i < 4; i++)
    tile[ty + i * 8][tx] = src[(size_t)(r0 + ty + i * 8) * C + c0 + tx];
  __syncthreads();
#pragma unroll
  for (int i = 0; i < 4; i++)
    dst[(size_t)(c0 + ty + i * 8) * R + r0 + tx] =
        (unsigned short)f2bf(tile[tx][ty + i * 8]);
}

// ---- G1: H[slot][h] = gelu(X @ W1^T + b1); block = 64-token tile x h-half --------
__global__ __launch_bounds__(256, 2) void g1_kernel(
    const float* __restrict__ x, const unsigned short* __restrict__ w1t,
    const float* __restrict__ b1, const int* __restrict__ cnts,
    const int* __restrict__ list, unsigned short* __restrict__ H) {
  __shared__ __align__(16) unsigned short Xf[64 * DM];  // 32 KB, A-frag order
  int bx = blockIdx.x;
  int hh = bx & 1, tb = bx >> 1;
  int base, s0, cnt;
  int e = decode_tile(cnts, tb, &base, &s0, &cnt);
  if (e < 0) return;

  int tid = threadIdx.x, w = tid >> 6, lane = tid & 63;
  int quad = lane >> 4, l16 = lane & 15;

  {  // stage Xf: wave w stages m-tile mt=w (lane-linear writes)
    int tl = w * 16 + l16;
    int token = (base + tl < cnt) ? list[e * TT + base + tl] : -1;
    unsigned short* dst0 = Xf + ((w * 8) * 64 + lane) * 8;
    if (token >= 0) {
      const float* xr = x + (size_t)token * DM + quad * 8;
#pragma unroll
      for (int ks = 0; ks < 8; ks++) {
        float4 v0 = *reinterpret_cast<const float4*>(xr + ks * 32);
        float4 v1 = *reinterpret_cast<const float4*>(xr + ks * 32 + 4);
        uint4 pk;
        pk.x = f2bf(v0.x) | (f2bf(v0.y) << 16);
        pk.y = f2bf(v0.z) | (f2bf(v0.w) << 16);
        pk.z = f2bf(v1.x) | (f2bf(v1.y) << 16);
        pk.w = f2bf(v1.z) | (f2bf(v1.w) << 16);
        *reinterpret_cast<uint4*>(dst0 + ks * 512) = pk;
      }
    } else {
      uint4 z = {0, 0, 0, 0};
#pragma unroll
      for (int ks = 0; ks < 8; ks++)
        *reinterpret_cast<uint4*>(dst0 + ks * 512) = z;
    }
  }
  __syncthreads();

  int h0 = hh * 256 + w * 64;
  const unsigned short* w1p =
      w1t + (size_t)e * HF * DM + (size_t)(h0 + l16) * DM + quad * 8;
  f32x4 pacc[4][4];
#pragma unroll
  for (int mt = 0; mt < 4; mt++)
#pragma unroll
    for (int nt = 0; nt < 4; nt++) pacc[mt][nt] = (f32x4){0.f, 0.f, 0.f, 0.f};

#pragma unroll
  for (int ks = 0; ks < 8; ks++) {
    bf16x8 bfr[4], afr[4];
#pragma unroll
    for (int nt = 0; nt < 4; nt++)
      bfr[nt] = *reinterpret_cast<const bf16x8*>(w1p + (size_t)(nt * 16) * DM + ks * 32);
#pragma unroll
    for (int mt = 0; mt < 4; mt++)
      afr[mt] = *reinterpret_cast<const bf16x8*>(Xf + ((mt * 8 + ks) * 64 + lane) * 8);
#pragma unroll
    for (int mt = 0; mt < 4; mt++)
#pragma unroll
      for (int nt = 0; nt < 4; nt++)
        pacc[mt][nt] = __builtin_amdgcn_mfma_f32_16x16x32_bf16(afr[mt], bfr[nt], pacc[mt][nt], 0, 0, 0);
  }

  float b1v[4];
#pragma unroll
  for (int nt = 0; nt < 4; nt++) b1v[nt] = b1[e * HF + h0 + nt * 16 + l16];

#pragma unroll
  for (int mt = 0; mt < 4; mt++) {
    size_t hrow = (size_t)(s0 + base + mt * 16 + quad * 4) * HF + h0 + l16;
#pragma unroll
    for (int r = 0; r < 4; r++) {
#pragma unroll
      for (int nt = 0; nt < 4; nt++) {
        float v = pacc[mt][nt][r] + b1v[nt];
        float g = 0.5f * v * (1.0f + erff(v * 0.70710678118654752f));
        H[hrow + (size_t)r * HF + nt * 16] = (unsigned short)f2bf(g);
      }
    }
  }
}

// ---- G2: Y[slot] = H[slot] @ W2^T, written IN PLACE over H (no atomics) ----------
// Block = 32-token tile (rows block-exclusive). m=token, n=d, k=512 full.
// H (bf16 row, 1KB) is fully consumed before Y (fp32 row, 1KB) overwrites it;
// __syncthreads() after the k-loop guards cross-wave read/overwrite.
__global__ __launch_bounds__(256, 2) void g2_kernel(
    const unsigned short* H, const unsigned short* __restrict__ w2t,
    const int* __restrict__ cnts, float* Y) {
  int base, s0;
  int e = decode_tile32(cnts, blockIdx.x, &base, &s0);
  if (e < 0) return;

  int tid = threadIdx.x, w = tid >> 6, lane = tid & 63;
  int quad = lane >> 4, l16 = lane & 15;

  const unsigned short* Hp = H + (size_t)(s0 + base + l16) * HF + quad * 8;
  const unsigned short* w2p =
      w2t + (size_t)e * DM * HF + (size_t)(w * 64 + l16) * HF + quad * 8;

  f32x4 oacc[2][4];
#pragma unroll
  for (int mt = 0; mt < 2; mt++)
#pragma unroll
    for (int nt = 0; nt < 4; nt++) oacc[mt][nt] = (f32x4){0.f, 0.f, 0.f, 0.f};

#pragma unroll
  for (int ks = 0; ks < 16; ks++) {
    bf16x8 ha[2], bfr[4];
#pragma unroll
    for (int mt = 0; mt < 2; mt++)
      ha[mt] = *reinterpret_cast<const bf16x8*>(Hp + (size_t)(mt * 16) * HF + ks * 32);
#pragma unroll
    for (int nt = 0; nt < 4; nt++)
      bfr[nt] = *reinterpret_cast<const bf16x8*>(w2p + (size_t)(nt * 16) * HF + ks * 32);
#pragma unroll
    for (int mt = 0; mt < 2; mt++)
#pragma unroll
      for (int nt = 0; nt < 4; nt++)
        oacc[mt][nt] = __builtin_amdgcn_mfma_f32_16x16x32_bf16(ha[mt], bfr[nt], oacc[mt][nt], 0, 0, 0);
  }

  __syncthreads();  // all waves done consuming this tile's H rows

  float* Yb = Y + (size_t)(s0 + base) * DM + w * 64;
#pragma unroll
  for (int mt = 0; mt < 2; mt++) {
#pragma unroll
    for (int r = 0; r < 4; r++) {
      float* Yr = Yb + (size_t)(mt * 16 + quad * 4 + r) * DM;
#pragma unroll
      for (int nt = 0; nt < 4; nt++)
        Yr[nt * 16 + l16] = oacc[mt][nt][r];
    }
  }
}

// ---- combine: out[t] = Y[slot1] + Y[slot2] + b2[e1] + b2[e2] ---------------------
__global__ __launch_bounds__(256) void combine_kernel(
    const float* __restrict__ Y, const uint2* __restrict__ slots,
    const float* __restrict__ b2, const int* __restrict__ cnts,
    float* __restrict__ out) {
  int s0p[NE];
  {
    int sp = 0;
#pragma unroll
    for (int i = 0; i < NE; i++) { s0p[i] = sp; sp += (cnts[i] + 63) & ~63; }
  }
  int tid = threadIdx.x;
  int t = blockIdx.x * 64 + (tid >> 2);
  int c0 = (tid & 3) * 64;
  uint2 s = slots[t];
  int e1 = s.x >> 14, r1 = s.x & 16383;
  int e2 = s.y >> 14, r2 = s.y & 16383;
  const float* y1 = Y + (size_t)(s0p[e1] + r1) * DM + c0;
  const float* y2 = Y + (size_t)(s0p[e2] + r2) * DM + c0;
  const float* q1 = b2 + e1 * DM + c0;
  const float* q2 = b2 + e2 * DM + c0;
  float* o = out + (size_t)t * DM + c0;
#pragma unroll
  for (int j = 0; j < 16; j++) {
    float4 a = *reinterpret_cast<const float4*>(y1 + j * 4);
    float4 b = *reinterpret_cast<const float4*>(y2 + j * 4);
    float4 p = *reinterpret_cast<const float4*>(q1 + j * 4);
    float4 q = *reinterpret_cast<const float4*>(q2 + j * 4);
    float4 r;
    r.x = a.x + b.x + p.x + q.x;
    r.y = a.y + b.y + p.y + q.y;
    r.z = a.z + b.z + p.z + q.z;
    r.w = a.w + b.w + p.w + q.w;
    *reinterpret_cast<float4*>(o + j * 4) = r;
  }
}

extern "C" void kernel_launch(void* const* d_in, const int* in_sizes, int n_in,
                              void* d_out, int out_size, void* d_ws, size_t ws_size,
                              hipStream_t stream) {
  (void)in_sizes; (void)n_in; (void)out_size; (void)ws_size;
  const float* x  = (const float*)d_in[0];
  const float* Wg = (const float*)d_in[1];
  const float* bg = (const float*)d_in[2];
  const float* W1 = (const float*)d_in[3];
  const float* b1 = (const float*)d_in[4];
  const float* W2 = (const float*)d_in[5];
  const float* b2 = (const float*)d_in[6];
  float* out = (float*)d_out;

  char* ws = (char*)d_ws;
  int* cnts = (int*)ws;                                       // 256 B
  int* list = (int*)(ws + 256);                               // 512 KB
  uint2* slots = (uint2*)(ws + 256 + 524288);                 // 128 KB
  unsigned short* w1t = (unsigned short*)(ws + 256 + 524288 + 131072);            // 2 MB
  unsigned short* w2t = (unsigned short*)(ws + 256 + 524288 + 131072 + 2097152);  // 2 MB
  size_t off_H = 256 + 524288 + 131072 + 2097152 + 2097152;
  unsigned short* Hbuf = (unsigned short*)(ws + off_H);       // ~34 MB (bf16 H, then fp32 Y)
  float* Ybuf = (float*)(ws + off_H);                         // same memory: 1KB rows

  hipMemsetAsync(cnts, 0, 256, stream);

  hipLaunchKernelGGL(gate_kernel, dim3(TT / 32), dim3(256), 0, stream,
                     x, Wg, bg, cnts, list, slots);
  hipLaunchKernelGGL(transpose_kernel, dim3(2 * NE * 128), dim3(256), 0, stream,
                     W1, W2, w1t, w2t);
  hipLaunchKernelGGL(g1_kernel, dim3(2 * MAXT), dim3(256), 0, stream,
                     x, w1t, b1, cnts, list, Hbuf);
  hipLaunchKernelGGL(g2_kernel, dim3(MAXT32), dim3(256), 0, stream,
                     Hbuf, w2t, cnts, Ybuf);
  hipLaunchKernelGGL(combine_kernel, dim3(TT / 64), dim3(256), 0, stream,
                     Ybuf, slots, b2, cnts, out);
}